// Round 15
// baseline (91.656 us; speedup 1.0000x reference)
//
#include <hip/hip_runtime.h>
#include <math.h>

#define BB 8
#define CC 64
#define HH 32
#define WW 32
#define HW 1024
#define NEGN 256
#define TEMP 2.0f
#define FACTOR 0.8f
#define EPSF 1e-8f

typedef short bf16x8 __attribute__((ext_vector_type(8)));
typedef float f32x4  __attribute__((ext_vector_type(4)));

__device__ inline unsigned short f2bf(float f) {     // RNE fp32 -> bf16
    unsigned u = __float_as_uint(f);
    u += 0x7FFFu + ((u >> 16) & 1u);
    return (unsigned short)(u >> 16);
}

// workspace: simPart f32[512*256] | sim0Part f32[512]
// partials stored (never accumulated). ALL cross-block handoff across the
// single dispatch boundary; NO in-kernel device fences (R12 lesson).

// ---------------------------------------------------------------------------
// K1 gemm_fused: prep_z2 is GONE — the z2 bf16 conversion + normq now happen
// inside the MFMA loop:
//   For tile q0t, lane (lg, ln15) loads fp32 z2[c][q0t+ln15] for its 16 c's
//   (64B-coalesced per 16-lane group; z2 is 8MB -> L2-resident after first
//   touch), computes the partial square-sum, shfl_xor(16,32) -> full normq
//   of its row (the exact value its epilogue lane needs), f2bf's the SAME
//   values the old prep produced -> bit-identical MFMA inputs.
//   64x redundant conversion VALU (~0.5us) + ~131MB L2 re-reads (~4us agg)
//   buys: one dispatch + gap (~7us) and 2MB of z2t/normq round-trips.
// Everything else byte-identical to passing R14:
//   (1) nidx int2 loads -> regs   (2) imgs staged (own 12KB buffer)
//   (3) z1 A-frags + z1sq in regs (shfl pattern)  -- barrier 1 --
//   (4) MFMA + in-loop B-convert; cos -> Dt_s  (5) weight phase
//   -- barrier 2 -- (6) gather/combine -- barrier 3 -- simpart alias
//   -- barrier 4 -- per-n sweep -> simPart; sim0Part.
// LDS: 64 + 12 + 0.07 = 76.1 KB -> 2 blocks/CU; grid 512 = 2/CU.
// ---------------------------------------------------------------------------
__global__ __launch_bounds__(256, 2) void gemm_fused(
    const float* __restrict__ z1,             // (B, C, HW)
    const float* __restrict__ z2,             // (B, C, HW)
    const float* __restrict__ img,            // (3, HW)
    const int*   __restrict__ nidx,           // (B, 2, HW, NEG)
    float* __restrict__ simPart,              // (512, NEG)
    float* __restrict__ sim0Part)             // (512)
{
    __shared__ float Dt_s[16 * HW];    // 64 KB: cos, later simpart alias
    __shared__ float imgs_l[3 * HW];   // 12 KB
    __shared__ float z1sq_s[16];

    const int t    = threadIdx.x;
    const int blk  = blockIdx.x;       // = b*64 + ptile
    const int b    = blk >> 6;
    const int p0   = (blk & 63) * 16;
    const int wave = t >> 6;
    const int lane = t & 63;
    const int ln15 = lane & 15;
    const int lg   = lane >> 4;        // k-chunk group 0..3

    // ---- (1) nidx loads FIRST (cold HBM; awaited in the weight phase) ----
    const int p_b = t >> 4;            // 0..15
    const int tn  = t & 15;
    const size_t nbase = ((size_t)(b * 2) * HW + p0 + p_b) * NEGN;
    const int2* __restrict__ nr = reinterpret_cast<const int2*>(nidx + nbase);
    const int2* __restrict__ nc =
        reinterpret_cast<const int2*>(nidx + nbase + (size_t)HW * NEGN);
    int2 rrv[8], ccv[8];
    #pragma unroll
    for (int j = 0; j < 8; ++j) {
        rrv[j] = nr[tn + 16 * j];
        ccv[j] = nc[tn + 16 * j];
    }

    // ---- (2) stage imgs (own buffer; staged once, up front) ----
    {
        const float4* __restrict__ imgf4 = reinterpret_cast<const float4*>(img);
        float4* imgs4 = reinterpret_cast<float4*>(imgs_l);
        #pragma unroll
        for (int j = 0; j < 3; ++j) imgs4[t + 256 * j] = imgf4[t + 256 * j];
    }

    // ---- (3) register-resident A-frags + z1 norms (verified R14 pattern) ----
    const float* __restrict__ z1p = z1 + (size_t)(b * CC) * HW + p0 + ln15;
    float av0[8], av1[8];
    #pragma unroll
    for (int j = 0; j < 8; ++j) {
        av0[j] = z1p[(size_t)(lg * 8 + j) * HW];
        av1[j] = z1p[(size_t)(32 + lg * 8 + j) * HW];
    }
    float zsq = 0.f;
    #pragma unroll
    for (int j = 0; j < 8; ++j) zsq += av0[j] * av0[j];
    #pragma unroll
    for (int j = 0; j < 8; ++j) zsq += av1[j] * av1[j];
    zsq += __shfl_xor(zsq, 16);
    zsq += __shfl_xor(zsq, 32);        // full z1sq of row ln15, every lane
    const float z1n_mine = sqrtf(zsq);
    float z1n_row[4];
    #pragma unroll
    for (int i = 0; i < 4; ++i) z1n_row[i] = __shfl(z1n_mine, lg * 4 + i);

    bf16x8 a0, a1;
    #pragma unroll
    for (int j = 0; j < 8; ++j) {
        a0[j] = (short)f2bf(av0[j]);
        a1[j] = (short)f2bf(av1[j]);
    }
    if (wave == 0 && lane < 16) z1sq_s[lane] = zsq;

    __syncthreads();                   // barrier 1: imgs + z1sq_s visible

    // ---- (4) MFMA over this wave's 16 q-tiles, B converted in-loop ----
    const int qw = wave * 256;
    const float* __restrict__ z2p = z2 + (size_t)(b * CC) * HW;
    #pragma unroll 4
    for (int tile = 0; tile < 16; ++tile) {
        const int q0t  = qw + tile * 16;
        const int qrow = q0t + ln15;
        float bv0[8], bv1[8];
        #pragma unroll
        for (int j = 0; j < 8; ++j) {
            bv0[j] = z2p[(size_t)(lg * 8 + j) * HW + qrow];
            bv1[j] = z2p[(size_t)(32 + lg * 8 + j) * HW + qrow];
        }
        float qsq = 0.f;
        #pragma unroll
        for (int j = 0; j < 8; ++j) qsq += bv0[j] * bv0[j];
        #pragma unroll
        for (int j = 0; j < 8; ++j) qsq += bv1[j] * bv1[j];
        qsq += __shfl_xor(qsq, 16);
        qsq += __shfl_xor(qsq, 32);    // full |z2 row qrow|^2
        const float pn = sqrtf(qsq);

        bf16x8 b0, b1;
        #pragma unroll
        for (int j = 0; j < 8; ++j) {
            b0[j] = (short)f2bf(bv0[j]);
            b1[j] = (short)f2bf(bv1[j]);
        }
        f32x4 acc = {0.f, 0.f, 0.f, 0.f};
        acc = __builtin_amdgcn_mfma_f32_16x16x32_bf16(a0, b0, acc, 0, 0, 0);
        acc = __builtin_amdgcn_mfma_f32_16x16x32_bf16(a1, b1, acc, 0, 0, 0);
        #pragma unroll
        for (int i = 0; i < 4; ++i) {
            const int row = lg * 4 + i;
            Dt_s[row * HW + q0t + ln15] =
                acc[i] / fmaxf(z1n_row[i] * pn, EPSF);
        }
    }

    // ---- (5) weight phase (no Dt_s dependence -> before barrier 2) ----
    const int pg = p0 + p_b;
    const float cen0 = imgs_l[pg], cen1 = imgs_l[HW + pg], cen2 = imgs_l[2 * HW + pg];
    const float hp = (float)(pg >> 5), wp = (float)(pg & 31);

    int qv[16];
    float se = 0.f, sr = 0.f;
    #pragma unroll
    for (int j = 0; j < 8; ++j) {
        {
            const int q = rrv[j].x * WW + ccv[j].x; qv[2 * j] = q;
            const float dh = hp - (float)rrv[j].x, dw = wp - (float)ccv[j].x;
            se += dh * dh + dw * dw;
            const float d0 = cen0 - imgs_l[q];
            const float d1 = cen1 - imgs_l[HW + q];
            const float d2 = cen2 - imgs_l[2 * HW + q];
            sr += d0 * d0 + d1 * d1 + d2 * d2;
        }
        {
            const int q = rrv[j].y * WW + ccv[j].y; qv[2 * j + 1] = q;
            const float dh = hp - (float)rrv[j].y, dw = wp - (float)ccv[j].y;
            se += dh * dh + dw * dw;
            const float d0 = cen0 - imgs_l[q];
            const float d1 = cen1 - imgs_l[HW + q];
            const float d2 = cen2 - imgs_l[2 * HW + q];
            sr += d0 * d0 + d1 * d1 + d2 * d2;
        }
    }
    #pragma unroll
    for (int off = 8; off; off >>= 1) {      // reduce within the 16-lane p-group
        se += __shfl_xor(se, off);
        sr += __shfl_xor(sr, off);
    }
    const float euc_norm = sqrtf((float)((HH - 1) * (HH - 1) + (WW - 1) * (WW - 1)));
    const float weight = sqrtf(se) / euc_norm * FACTOR +
                         sqrtf(sr) / sqrtf(3.0f) * (1.0f - FACTOR);

    __syncthreads();                   // barrier 2: all Dt_s writes done

    // ---- (6) gather cos, combine, per-n block sums ----
    float2 sv[8];
    #pragma unroll
    for (int j = 0; j < 8; ++j) {
        const float c0 = Dt_s[p_b * HW + qv[2 * j]];
        const float c1 = Dt_s[p_b * HW + qv[2 * j + 1]];
        sv[j].x = fminf(fabsf(c0 * weight), 1.0f);
        sv[j].y = fminf(fabsf(c1 * weight), 1.0f);
    }
    __syncthreads();                   // barrier 3: Dt_s reads done -> alias

    float2* simpart2 = reinterpret_cast<float2*>(Dt_s);  // [16][128]
    #pragma unroll
    for (int j = 0; j < 8; ++j)
        simpart2[p_b * (NEGN / 2) + tn + 16 * j] = sv[j];
    __syncthreads();                   // barrier 4

    float s = 0.f;
    #pragma unroll
    for (int pp = 0; pp < 16; ++pp) s += Dt_s[pp * NEGN + t];
    simPart[(size_t)blk * NEGN + t] = s;

    if (t == 0) {
        float s0 = 0.f;
        #pragma unroll
        for (int pp = 0; pp < 16; ++pp)
            s0 += fminf(fabsf(z1sq_s[pp] / fmaxf(z1sq_s[pp], EPSF)), 1.0f);
        sim0Part[blk] = s0;
    }
}

// ---------------------------------------------------------------------------
// reduce_out: identical to the passing R13/R14 kernel.
// ---------------------------------------------------------------------------
__global__ __launch_bounds__(256) void reduce_out(
    const float* __restrict__ simPart,   // (512, NEG)
    const float* __restrict__ sim0Part,  // (512)
    float* __restrict__ out)
{
    const int b = blockIdx.x;
    const int t = threadIdx.x;

    float a = 0.f;
    #pragma unroll 8
    for (int pblk = 0; pblk < 64; ++pblk)
        a += simPart[((size_t)(b * 64 + pblk)) * NEGN + t];

    const float s = a * (1.0f / HW) * (1.0f / TEMP);
    float ssum = s;
    float lsum = fmaxf(log1pf(-s), -100.0f);

    __shared__ float rs[4], rl[4];
    __shared__ float s0sh;
    #pragma unroll
    for (int off = 32; off; off >>= 1) {
        ssum += __shfl_down(ssum, off);
        lsum += __shfl_down(lsum, off);
    }
    if ((t & 63) == 0) { rs[t >> 6] = ssum; rl[t >> 6] = lsum; }

    if (t < 64) {
        float v = sim0Part[b * 64 + t];
        #pragma unroll
        for (int off = 32; off; off >>= 1) v += __shfl_xor(v, off);
        if (t == 0) s0sh = v * (1.0f / HW);
    }
    __syncthreads();

    if (t == 0) {
        const float S = rs[0] + rs[1] + rs[2] + rs[3];
        const float L = rl[0] + rl[1] + rl[2] + rl[3];
        const float s0 = s0sh;
        const float logp = fmaxf(logf(s0), -100.0f);
        atomicAdd(out + 0, -(logp + L) / ((float)(NEGN + 1) * (float)BB));
        atomicAdd(out + 1, s0 / (float)BB);
        atomicAdd(out + 2, S / (float)NEGN * TEMP / (float)BB);
    }
}

extern "C" void kernel_launch(void* const* d_in, const int* in_sizes, int n_in,
                              void* d_out, int out_size, void* d_ws, size_t ws_size,
                              hipStream_t stream) {
    const float* v1   = (const float*)d_in[0];
    const float* v2   = (const float*)d_in[1];
    const float* img  = (const float*)d_in[2];
    const int*   nidx = (const int*)  d_in[3];

    float* simPart  = (float*)d_ws;                   // 512*256
    float* sim0Part = simPart + 512 * NEGN;           // 512

    gemm_fused<<<512, 256, 0, stream>>>(v1, v2, img, nidx, simPart, sim0Part);
    reduce_out<<<BB, 256, 0, stream>>>(simPart, sim0Part, (float*)d_out);
}